// Round 6
// baseline (818.209 us; speedup 1.0000x reference)
//
#include <hip/hip_runtime.h>
#include <math.h>

// GCN_homo: h = relu(D^-1/2 (A+I) D^-1/2 (x@Wg) + bg); MLP 16->16->32->1; sigmoid.
// N=100000, F=512, E=3200000. fp32; edge_index int32.
// R6: EPB 16384->4096 (196->782 blocks: partition passes were 10% occupancy,
// latency-bound); bh bucket-major so colscan streams contiguously; MLP fused
// into gather via quad shfl_xor reduction (drops h round-trip + 1 launch).

static constexpr int F = 512;
static constexpr int C = 16;
static constexpr int BSH = 7;       // 128 nodes per bucket
static constexpr int BSZ = 128;
static constexpr int NBMAX = 1024;  // max buckets (n <= 131072)
static constexpr int EPB = 4096;    // edges per partition block

// K1: xw[row] = x[row] @ Wg.
__global__ __launch_bounds__(256) void k_xw(const float* __restrict__ x,
                                            const float* __restrict__ Wg,
                                            float* __restrict__ xw, int n)
{
    int row = blockIdx.x * 256 + threadIdx.x;
    if (row >= n) return;
    float acc[C];
#pragma unroll
    for (int c = 0; c < C; ++c) acc[c] = 0.f;
    const float4* xr = (const float4*)(x + (size_t)row * F);
#pragma unroll 4
    for (int k4 = 0; k4 < F / 4; ++k4) {
        float4 xv = xr[k4];
        const float* w = Wg + k4 * 4 * C;  // uniform -> s_load
#pragma unroll
        for (int j = 0; j < 4; ++j) {
            float xs = (j == 0) ? xv.x : (j == 1) ? xv.y : (j == 2) ? xv.z : xv.w;
#pragma unroll
            for (int c = 0; c < C; ++c)
                acc[c] = fmaf(xs, w[j * C + c], acc[c]);
        }
    }
    float4* o = (float4*)(xw + (size_t)row * C);
#pragma unroll
    for (int q = 0; q < 4; ++q)
        o[q] = make_float4(acc[4 * q + 0], acc[4 * q + 1], acc[4 * q + 2], acc[4 * q + 3]);
}

// Per-block bucket histogram -> bh[bucket][block] (bucket-major). No global atomics.
__global__ __launch_bounds__(256) void k_bcount(const int* __restrict__ dst,
                                                int* __restrict__ bh, int E, int geb)
{
    __shared__ int hist[NBMAX];
    for (int i = threadIdx.x; i < NBMAX; i += 256) hist[i] = 0;
    __syncthreads();
    int base = blockIdx.x * EPB;
#pragma unroll 4
    for (int j = 0; j < EPB / 256; ++j) {
        int e = base + j * 256 + threadIdx.x;
        if (e < E) atomicAdd(&hist[dst[e] >> BSH], 1);
    }
    __syncthreads();
    for (int i = threadIdx.x; i < NBMAX; i += 256)
        bh[(size_t)i * geb + blockIdx.x] = hist[i];
}

// Column scan: thread b streams its contiguous bh row, exclusive scan in place.
__global__ __launch_bounds__(256) void k_colscan(int* __restrict__ bh,
                                                 int* __restrict__ total, int geb)
{
    int b = blockIdx.x * 256 + threadIdx.x;  // grid 4x256 = NBMAX
    int* row = bh + (size_t)b * geb;
    int run = 0;
    for (int g = 0; g < geb; ++g) {
        int v = row[g];
        row[g] = run;
        run += v;
    }
    total[b] = run;
}

// Exclusive scan of bucket totals -> bstart[0..NBMAX].
__global__ __launch_bounds__(1024) void k_bscan(const int* __restrict__ total,
                                                int* __restrict__ bstart)
{
    __shared__ int sh[NBMAX];
    int t = threadIdx.x;
    int v = total[t];
    sh[t] = v;
    __syncthreads();
    for (int d = 1; d < NBMAX; d <<= 1) {
        int u = (t >= d) ? sh[t - d] : 0;
        __syncthreads();
        sh[t] += u;
        __syncthreads();
    }
    bstart[t] = sh[t] - v;
    if (t == NBMAX - 1) bstart[NBMAX] = sh[t];
}

// Partition: absolute cursors = bstart + own prefix; LDS atomics only.
__global__ __launch_bounds__(256) void k_bscatter(const int* __restrict__ ei,
                                                  const int* __restrict__ bh,
                                                  const int* __restrict__ bstart,
                                                  int* __restrict__ packed, int E, int geb)
{
    __shared__ int cur[NBMAX];
    int g = blockIdx.x;
    for (int i = threadIdx.x; i < NBMAX; i += 256)
        cur[i] = bstart[i] + bh[(size_t)i * geb + g];
    __syncthreads();
    int base = g * EPB;
#pragma unroll 2
    for (int j = 0; j < EPB / 256; ++j) {
        int e = base + j * 256 + threadIdx.x;
        if (e < E) {
            int d = ei[E + e];
            int s = ei[e];
            int b = d >> BSH;
            int r = atomicAdd(&cur[b], 1);
            packed[r] = s | ((d & (BSZ - 1)) << 17);
        }
    }
}

// Per-bucket CSR build: LDS hist -> local scan -> srcs/starts/cnt/dinv;
// scales this bucket's y rows in place.
__global__ __launch_bounds__(256) void k_bcsr(const int* __restrict__ packed,
                                              const int* __restrict__ bstart,
                                              float* __restrict__ y,
                                              int* __restrict__ srcs,
                                              int* __restrict__ starts,
                                              int* __restrict__ cnt,
                                              float* __restrict__ dinv, int n)
{
    int b = blockIdx.x, t = threadIdx.x;
    __shared__ int hist[BSZ];
    __shared__ int sc[BSZ];
    __shared__ float sdi[BSZ];
    if (t < BSZ) hist[t] = 0;
    __syncthreads();
    int beg = bstart[b], end = bstart[b + 1];
    for (int e = beg + t; e < end; e += 256)
        atomicAdd(&hist[(packed[e] >> 17) & (BSZ - 1)], 1);
    __syncthreads();
    int myc = 0;
    if (t < BSZ) { myc = hist[t]; sc[t] = myc; }
    __syncthreads();
    for (int d = 1; d < BSZ; d <<= 1) {
        int u = 0;
        if (t < BSZ && t >= d) u = sc[t - d];
        __syncthreads();
        if (t < BSZ) sc[t] += u;
        __syncthreads();
    }
    int node0 = b << BSH;
    if (t < BSZ) {
        int lst = sc[t] - myc;   // exclusive local offset
        sc[t] = lst;
        float di = rsqrtf((float)(myc + 1));
        sdi[t] = di;
        int node = node0 + t;
        if (node < n) { starts[node] = beg + lst; cnt[node] = myc; dinv[node] = di; }
        hist[t] = 0;             // reuse as cursor
    }
    __syncthreads();
    for (int e = beg + t; e < end; e += 256) {
        int p = packed[e];
        int dl = (p >> 17) & (BSZ - 1);
        int r = atomicAdd(&hist[dl], 1);
        srcs[beg + sc[dl] + r] = p & 0x1FFFF;
    }
    // scale this bucket's y rows by dinv
    int nn = n - node0; if (nn > BSZ) nn = BSZ;
    if (nn <= 0) return;
    int lim = nn * 4;
    float4* yv = (float4*)(y + (size_t)node0 * C);
    for (int i = t; i < lim; i += 256) {
        float di = sdi[i >> 2];
        float4 v = yv[i];
        v.x *= di; v.y *= di; v.z *= di; v.w *= di;
        yv[i] = v;
    }
}

// Gather + fused MLP. 4 lanes/node (quad q owns channels 4q..4q+3).
// Register-accumulated gather; h@W1 via per-quad partials + 2x shfl_xor
// quad-reduction (no dynamic register indexing); layers 2-3 redundant/lane.
__global__ __launch_bounds__(256) void k_gather_mlp(const float* __restrict__ y,
                                                    const int* __restrict__ srcs,
                                                    const int* __restrict__ starts,
                                                    const int* __restrict__ cnt,
                                                    const float* __restrict__ dinv,
                                                    const float* __restrict__ bg,
                                                    const float* __restrict__ W1,
                                                    const float* __restrict__ b1,
                                                    const float* __restrict__ W2,
                                                    const float* __restrict__ b2,
                                                    const float* __restrict__ W3,
                                                    const float* __restrict__ b3,
                                                    float* __restrict__ out, int n)
{
    int tid = blockIdx.x * 256 + threadIdx.x;
    int i = tid >> 2;
    if (i >= n) return;          // whole quads retire together (n*4 granularity)
    int q = tid & 3;
    const float4* yv = (const float4*)y;
    float4 acc = yv[(size_t)i * 4 + q];  // self-loop term (y pre-scaled)
    int beg = starts[i];
    int end = beg + cnt[i];
    int e = beg;
    int headEnd = (beg + 3) & ~3;
    if (headEnd > end) headEnd = end;
    for (; e < headEnd; ++e) {
        float4 v = yv[(size_t)srcs[e] * 4 + q];
        acc.x += v.x; acc.y += v.y; acc.z += v.z; acc.w += v.w;
    }
    for (; e + 4 <= end; e += 4) {
        int4 s4 = *(const int4*)(srcs + e);
        float4 v0 = yv[(size_t)s4.x * 4 + q];
        float4 v1 = yv[(size_t)s4.y * 4 + q];
        float4 v2 = yv[(size_t)s4.z * 4 + q];
        float4 v3 = yv[(size_t)s4.w * 4 + q];
        acc.x += v0.x + v1.x + v2.x + v3.x;
        acc.y += v0.y + v1.y + v2.y + v3.y;
        acc.z += v0.z + v1.z + v2.z + v3.z;
        acc.w += v0.w + v1.w + v2.w + v3.w;
    }
    for (; e < end; ++e) {
        float4 v = yv[(size_t)srcs[e] * 4 + q];
        acc.x += v.x; acc.y += v.y; acc.z += v.z; acc.w += v.w;
    }
    float di = dinv[i];
    const float* bq = bg + q * 4;
    float r0 = fmaxf(fmaf(acc.x, di, bq[0]), 0.f);
    float r1 = fmaxf(fmaf(acc.y, di, bq[1]), 0.f);
    float r2 = fmaxf(fmaf(acc.z, di, bq[2]), 0.f);
    float r3 = fmaxf(fmaf(acc.w, di, bq[3]), 0.f);
    // partial h1: this quad's 4 k-rows of W1
    const float* w1r = W1 + q * 4 * 16;
    float p1[16];
#pragma unroll
    for (int c = 0; c < 16; ++c)
        p1[c] = fmaf(r0, w1r[c],
                fmaf(r1, w1r[16 + c],
                fmaf(r2, w1r[32 + c], r3 * w1r[48 + c])));
    // quad reduction (lanes i*4..i*4+3 are wave-aligned; masks 1,2 stay in quad)
#pragma unroll
    for (int c = 0; c < 16; ++c) {
        p1[c] += __shfl_xor(p1[c], 1);
        p1[c] += __shfl_xor(p1[c], 2);
    }
    float h1[16];
#pragma unroll
    for (int c = 0; c < 16; ++c) h1[c] = fmaxf(p1[c] + b1[c], 0.f);
    float h2[32];
#pragma unroll
    for (int c = 0; c < 32; ++c) {
        float s = b2[c];
#pragma unroll
        for (int k = 0; k < 16; ++k) s = fmaf(h1[k], W2[k * 32 + c], s);
        h2[c] = fmaxf(s, 0.f);
    }
    float s = b3[0];
#pragma unroll
    for (int k = 0; k < 32; ++k) s = fmaf(h2[k], W3[k], s);
    if (q == 0) out[i] = 1.f / (1.f + expf(-s));
}

extern "C" void kernel_launch(void* const* d_in, const int* in_sizes, int n_in,
                              void* d_out, int out_size, void* d_ws, size_t ws_size,
                              hipStream_t stream)
{
    const float* x  = (const float*)d_in[0];
    const int*   ei = (const int*)d_in[1];   // [2,E]: src at [e], dst at [E+e]
    const float* Wg = (const float*)d_in[2];
    const float* bg = (const float*)d_in[3];
    const float* W1 = (const float*)d_in[4];
    const float* b1 = (const float*)d_in[5];
    const float* W2 = (const float*)d_in[6];
    const float* b2 = (const float*)d_in[7];
    const float* W3 = (const float*)d_in[8];
    const float* b3 = (const float*)d_in[9];
    float* out = (float*)d_out;

    int n = in_sizes[0] / F;   // 100000
    int E = in_sizes[1] / 2;   // 3200000

    int gb  = (n + 255) / 256;
    int geb = (E + EPB - 1) / EPB;          // 782
    int NB  = (n + BSZ - 1) >> BSH;         // 782

    // ws: y[n*16] | packed[E] | srcs[E] (aliases bh[NBMAX*geb], disjoint
    //     lifetimes) | starts[n] | cnt[n] | dinv[n] | total[1024] | bstart[1025]
    char* ws = (char*)d_ws;
    size_t off = 0;
    float* y      = (float*)(ws + off); off += (size_t)n * C * sizeof(float);
    int*   packed = (int*)  (ws + off); off += (size_t)E * sizeof(int);
    int*   srcs   = (int*)  (ws + off);
    int*   bh     = srcs;  // alias, disjoint lifetime (bh: bcount..bscatter)
    size_t big = (size_t)E; if ((size_t)NBMAX * geb > big) big = (size_t)NBMAX * geb;
    off += big * sizeof(int);
    int*   starts = (int*)  (ws + off); off += (size_t)((n + 3) & ~3) * sizeof(int);
    int*   cnt    = (int*)  (ws + off); off += (size_t)((n + 3) & ~3) * sizeof(int);
    float* dinv   = (float*)(ws + off); off += (size_t)((n + 3) & ~3) * sizeof(float);
    int*   total  = (int*)  (ws + off); off += NBMAX * sizeof(int);
    int*   bstart = (int*)  (ws + off);

    k_xw<<<gb, 256, 0, stream>>>(x, Wg, y, n);
    k_bcount<<<geb, 256, 0, stream>>>(ei + E, bh, E, geb);
    k_colscan<<<NBMAX / 256, 256, 0, stream>>>(bh, total, geb);
    k_bscan<<<1, 1024, 0, stream>>>(total, bstart);
    k_bscatter<<<geb, 256, 0, stream>>>(ei, bh, bstart, packed, E, geb);
    k_bcsr<<<NB, 256, 0, stream>>>(packed, bstart, y, srcs, starts, cnt, dinv, n);
    k_gather_mlp<<<(n * 4 + 255) / 256, 256, 0, stream>>>(y, srcs, starts, cnt, dinv,
                                                          bg, W1, b1, W2, b2, W3, b3, out, n);
}